// Round 2
// baseline (79.345 us; speedup 1.0000x reference)
//
#include <hip/hip_runtime.h>
#include <math.h>

#define NB 256
#define NIMG 1561
#define RIRLEN 8000
#define PADI 40
#define NTHREADS 1024
#define NWAVES (NTHREADS / 64)
#define NBKT 505          // bucket = (base+80)>>4, base in [-40,7999] -> 2..504
#define NSTARTP 512       // s_start padded to 512 (entries >=505 = total)
#define NPAIR 63          // pairs of 64-sample streams; pair q = streams 2q,2q+1
#define CHUNK 64          // records per phase-2 work item (per half-stream)
#define MAXITEMS 256      // worst-case sum of chunks ~118 (bound: 63 + sum(len)/64)

// ---------------------------------------------------------------------------
// Compile-time image-lattice table: all g in [-10,10]^3 with |g|_1 <= 10,
// meshgrid(ij) lexicographic order. Packed:
//   bits 0-4: x+10, 5-9: y+10, 10-14: z+10, 15-19: |g|_1
// ---------------------------------------------------------------------------
struct ImgTab { unsigned int v[NIMG]; };

constexpr ImgTab build_tab() {
    ImgTab t{};
    int n = 0;
    for (int x = -10; x <= 10; ++x)
        for (int y = -10; y <= 10; ++y)
            for (int z = -10; z <= 10; ++z) {
                int ax = x < 0 ? -x : x;
                int ay = y < 0 ? -y : y;
                int az = z < 0 ? -z : z;
                int l1 = ax + ay + az;
                if (l1 <= 10) {
                    t.v[n++] = (unsigned)(x + 10) | ((unsigned)(y + 10) << 5) |
                               ((unsigned)(z + 10) << 10) | ((unsigned)l1 << 15);
                }
            }
    return t;
}

constexpr int tab_count() {
    int n = 0;
    for (int x = -10; x <= 10; ++x)
        for (int y = -10; y <= 10; ++y)
            for (int z = -10; z <= 10; ++z) {
                int ax = x < 0 ? -x : x;
                int ay = y < 0 ? -y : y;
                int az = z < 0 ? -z : z;
                if (ax + ay + az <= 10) ++n;
            }
    return n;
}
static_assert(tab_count() == NIMG, "image count mismatch");

__constant__ ImgTab c_tab = build_tab();

// Record per image (bucket-sorted): (A, B, C, d)
//   A = 0.5*S, B = 0.5*S*cos(pi*d/40), C = 0.5*S*sin(pi*d/40)
//   S = (-1)^dlc * amp * sin(pi*frac)/pi,  d = delay (exact, NON-integer)
// Tap at sample n: (-1)^n * (A + B*cos(pi*n/40) + C*sin(pi*n/40)) / (n-d),
// masked to |n-d| < 40.  frac==0 records are emitted as exact spikes instead.
//
// Phase 2 work item = (pair q, chunk c): chunk c covers record indices
// [c*CHUNK, (c+1)*CHUNK) of EACH half-stream's bucket window. Partial sums
// are accumulated into a 32 KB LDS accumulator via ds f32 atomics (lanes hit
// consecutive banks -> 2-way max, free). Items are emitted in DESCENDING pair
// order: record density ~ delay^2 peaks at the room's delay cutoff, so the
// heaviest items are scheduled first (LPT) and empty pairs emit no items.
//
// LDS note: the item list ALIASES the histogram array (dead after the scan
// barrier) to stay clear of the 64 KB static-LDS limit (~63.7 KB total).
__global__ __launch_bounds__(NTHREADS) void
rir_kernel(const float* __restrict__ in, float* __restrict__ out) {
    __shared__ float4 s_rec[NIMG + 1];   // +1 dummy (zero) record
    __shared__ float  s_out[RIRLEN];     // per-block output accumulator (32 KB)
    __shared__ float  s_trpow[11];
    __shared__ int    s_hist[NSTARTP];   // phase 1: histogram; later: item list
    __shared__ int    s_start[NSTARTP];
    __shared__ int    s_cursor[NBKT];
    __shared__ int    s_T;
    __shared__ int    s_qnext;
    __shared__ int    s_nspike;
    __shared__ int    s_spike_idx[64];
    __shared__ float  s_spike_amp[64];

    int* const s_item = s_hist;          // alias: s_hist dead after scan barrier

    const int b   = blockIdx.x;
    const int tid = threadIdx.x;
    const float* p = in + b * 10;

    if (tid < NSTARTP) s_hist[tid] = 0;
    for (int i = tid; i < RIRLEN; i += NTHREADS) s_out[i] = 0.0f;
    if (tid == 0) {
        float tr = sqrtf(1.0f - p[9]);
        float pw = 1.0f;
        for (int k = 0; k <= 10; ++k) { s_trpow[k] = pw; pw *= tr; }
        s_nspike = 0;
        s_qnext  = NWAVES;
        s_rec[NIMG] = make_float4(0.0f, 0.0f, 0.0f, -1.0e6f);  // dummy
    }
    __syncthreads();

    const float rx = p[0], ry = p[1], rz = p[2];
    const float mx = p[3] * rx, my = p[4] * ry, mz = p[5] * rz;
    const float sx = p[6] * rx, sy = p[7] * ry, sz = p[8] * rz;
    const float K = 16000.0f / 343.0f;
    const float INV_PI = 0.31830988618379067154f;

    // ---- phase 1: per-image parameters + bucket histogram ----
    float4 rec[2];
    int ibkt[2]  = {0, 0};
    bool ivalid[2] = {false, false};

    for (int u = 0; u < 2; ++u) {
        int i = tid + u * NTHREADS;
        if (i < NIMG) {
            unsigned v = c_tab.v[i];
            int gx = (int)(v & 31u) - 10;
            int gy = (int)((v >> 5) & 31u) - 10;
            int gz = (int)((v >> 10) & 31u) - 10;
            int l1 = (int)(v >> 15);

            float ix = (gx & 1) ? rx * (float)(gx + 1) - sx : rx * (float)gx + sx;
            float iy = (gy & 1) ? ry * (float)(gy + 1) - sy : ry * (float)gy + sy;
            float iz = (gz & 1) ? rz * (float)(gz + 1) - sz : rz * (float)gz + sz;

            float dx = ix - mx, dy = iy - my, dz = iz - mz;
            float dist = sqrtf(dx * dx + dy * dy + dz * dz);

            float amp  = s_trpow[l1] * __builtin_amdgcn_rcpf(dist);
            float d    = dist * K;
            float dlc  = ceilf(d);
            float frac = dlc - d;                 // exact (Sterbenz)
            int   idlc = (int)dlc;
            int   base = idlc - PADI;

            if (base < RIRLEN) {
                if (frac == 0.0f) {
                    // integer-grid delay: exact single spike of amp at idlc
                    if (idlc < RIRLEN) {
                        int sp = atomicAdd(&s_nspike, 1);
                        if (sp < 64) { s_spike_idx[sp] = idlc; s_spike_amp[sp] = amp; }
                    }
                } else {
                    float spf = (frac < 1.0e-3f) ? frac : (sinpif(frac) * INV_PI);
                    float S   = amp * spf;
                    if (idlc & 1) S = -S;         // (-1)^dlc
                    float hS  = 0.5f * S;
                    float cd  = cospif(d * 0.025f);
                    float sd  = sinpif(d * 0.025f);
                    rec[u] = make_float4(hS, hS * cd, hS * sd, d);
                    ibkt[u]   = (base + 80) >> 4;
                    ivalid[u] = true;
                    atomicAdd(&s_hist[ibkt[u]], 1);
                }
            }
        }
    }
    __syncthreads();

    // ---- single-wave exclusive scan of the 505-bucket histogram ----
    // lane l owns buckets [8l, 8l+8); local prefix + shfl_up wave scan.
    if (tid < 64) {
        int base_i = tid * 8;
        int v[8], pre[8];
        int run = 0;
#pragma unroll
        for (int j = 0; j < 8; ++j) {
            v[j] = s_hist[base_i + j];            // padded entries are 0
            pre[j] = run;
            run += v[j];
        }
        int t = run;
#pragma unroll
        for (int d2 = 1; d2 < 64; d2 <<= 1) {
            int y = __shfl_up(t, d2);
            if (tid >= d2) t += y;
        }
        int excl = t - run;
#pragma unroll
        for (int j = 0; j < 8; ++j) {
            int idx = base_i + j;
            int sv  = excl + pre[j];              // exclusive prefix at idx
            s_start[idx] = sv;
            if (idx < NBKT) s_cursor[idx] = sv;
        }
    }
    __syncthreads();   // histogram dead from here; s_hist reused as s_item

    // ---- scatter records into bucket-sorted order ----
    for (int u = 0; u < 2; ++u) {
        if (ivalid[u]) {
            int pos = atomicAdd(&s_cursor[ibkt[u]], 1);
            s_rec[pos] = rec[u];
        }
    }

    // ---- wave 0: build phase-2 item list (s_start stable since scan barrier)
    // lane l handles pair q = 62-l  ->  items emitted in DESCENDING q order.
    if (tid < 64) {
        int nch = 0, q = 62 - tid;
        if (tid < NPAIR) {
            int lenA = s_start[8 * q + 9]  - s_start[8 * q];
            int lenB = s_start[8 * q + 13] - s_start[8 * q + 4];
            int ml   = (lenA > lenB) ? lenA : lenB;
            nch = (ml + CHUNK - 1) >> 6;
        }
        int run = nch;
#pragma unroll
        for (int d2 = 1; d2 < 64; d2 <<= 1) {
            int y = __shfl_up(run, d2);
            if (tid >= d2) run += y;
        }
        int excl = run - nch;
        int tot  = __shfl(run, 63);
        if (tid == 0) s_T = (tot < MAXITEMS) ? tot : MAXITEMS;
        for (int c = 0; c < nch; ++c)
            if (excl + c < MAXITEMS) s_item[excl + c] = (q << 5) | c;
    }
    __syncthreads();

    // ---- phase 2: gather. work item = (pair, chunk); wave serves 2 streams ----
    // lanes 0-31 -> stream 2q (h=0), lanes 32-63 -> stream 2q+1 (h=1);
    // each lane owns samples n0 and n0+32. Partial sums -> LDS f32 atomics.
    const int wave = tid >> 6;
    const int lane = tid & 63;
    const int h    = lane >> 5;
    const int l5   = lane & 31;
    const float sgn = (l5 & 1) ? -1.0f : 1.0f;    // (-1)^n, n parity == l5 parity
    const float c32 = -0.80901699437494742410f;   // cos(0.8*pi)
    const float s32 =  0.58778525229247312917f;   // sin(0.8*pi)
    float* __restrict__ ob = out + (size_t)b * RIRLEN;
    const int T = s_T;

    int idx = wave;
    while (idx < T) {
        const int item = s_item[idx];
        const int q = item >> 5, c = item & 31;
        const int n0 = (q << 7) + (h << 6) + l5;
        const int n1 = n0 + 32;
        const float fn0 = (float)n0;
        const float cn0 = cospif(fn0 * 0.025f), sn0 = sinpif(fn0 * 0.025f);
        const float cnn1 = cn0 * c32 - sn0 * s32; // cos(pi*n1/40)
        const float snn1 = sn0 * c32 + cn0 * s32; // sin(pi*n1/40)

        const int loA = s_start[8 * q];
        const int hiA = s_start[8 * q + 9];
        const int loB = s_start[8 * q + 4];
        const int hiB = s_start[8 * q + 13];
        const int lenA = hiA - loA, lenB = hiB - loB;
        const int lmn = (lenA < lenB) ? lenA : lenB;
        const int lmx = (lenA > lenB) ? lenA : lenB;
        const int st  = c << 6;                   // c * CHUNK
        int e0 = lmn - st; e0 = (e0 < 0) ? 0 : ((e0 > CHUNK) ? CHUNK : e0);
        int e1 = lmx - st; e1 = (e1 > CHUNK) ? CHUNK : e1;   // >0 since c<nch
        const int lo = (h ? loB : loA) + st;
        const int hi = h ? hiB : hiA;

        float acc0 = 0.0f, acc1 = 0.0f;
        // main loop: both halves in-range within this chunk, no index select.
        // shared-rcp trick: 1/x0 = x1*rcp(x0*x1), 1/x1 = x0*rcp(x0*x1)
        // (|x0*x1| in [~3e-6, 7.3e3], never 0 since d is non-integer).
#pragma clang loop unroll_count(8)
        for (int it = 0; it < e0; ++it) {
            float4 r = s_rec[lo + it];
            float x0 = fn0 - r.w;                 // never 0 (d non-integer)
            float x1 = x0 + 32.0f;
            float pr = __builtin_amdgcn_rcpf(x0 * x1);
            float t0 = fmaf(r.y, cn0, r.x);  t0 = fmaf(r.z, sn0, t0);
            float t1 = fmaf(r.y, cnn1, r.x); t1 = fmaf(r.z, snn1, t1);
            t0 = (fabsf(x0) < 40.0f) ? t0 : 0.0f; // hann support mask
            t1 = (fabsf(x1) < 40.0f) ? t1 : 0.0f;
            acc0 = fmaf(t0 * x1, pr, acc0);
            acc1 = fmaf(t1 * x0, pr, acc1);
        }
        // fixup: longer half continues, shorter half reads dummy record
#pragma clang loop unroll_count(4)
        for (int it = e0; it < e1; ++it) {
            int k = lo + it;
            float4 r = s_rec[(k < hi) ? k : NIMG];
            float x0 = fn0 - r.w;
            float x1 = x0 + 32.0f;
            float pr = __builtin_amdgcn_rcpf(x0 * x1);
            float t0 = fmaf(r.y, cn0, r.x);  t0 = fmaf(r.z, sn0, t0);
            float t1 = fmaf(r.y, cnn1, r.x); t1 = fmaf(r.z, snn1, t1);
            t0 = (fabsf(x0) < 40.0f) ? t0 : 0.0f;
            t1 = (fabsf(x1) < 40.0f) ? t1 : 0.0f;
            acc0 = fmaf(t0 * x1, pr, acc0);
            acc1 = fmaf(t1 * x0, pr, acc1);
        }
        if (n0 < RIRLEN) atomicAdd(&s_out[n0], acc0 * sgn);
        if (n1 < RIRLEN) atomicAdd(&s_out[n1], acc1 * sgn);

        // steal next item
        int nq;
        if (lane == 0) nq = atomicAdd(&s_qnext, 1);
        idx = __shfl(nq, 0);
    }

    // ---- spikes (frac==0, rare): add into LDS accumulator ----
    __syncthreads();
    int nsp = s_nspike; nsp = (nsp < 64) ? nsp : 64;
    if (tid < nsp) atomicAdd(&s_out[s_spike_idx[tid]], s_spike_amp[tid]);
    __syncthreads();

    // ---- final copy LDS -> global, vectorized ----
    float4* __restrict__ o4 = (float4*)ob;
    const float4* s4 = (const float4*)s_out;
#pragma unroll 2
    for (int i = tid; i < RIRLEN / 4; i += NTHREADS) o4[i] = s4[i];

    // time-of-arrival
    if (tid == 0) {
        float dx = mx - sx, dy = my - sy, dz = mz - sz;
        out[(size_t)NB * RIRLEN + b] = 40.0f + sqrtf(dx * dx + dy * dy + dz * dz) * K;
    }
}

extern "C" void kernel_launch(void* const* d_in, const int* in_sizes, int n_in,
                              void* d_out, int out_size, void* d_ws, size_t ws_size,
                              hipStream_t stream) {
    const float* in = (const float*)d_in[0];
    float* out = (float*)d_out;
    rir_kernel<<<dim3(NB), dim3(NTHREADS), 0, stream>>>(in, out);
}

// Round 3
// 77.353 us; speedup vs baseline: 1.0258x; 1.0258x over previous
//
#include <hip/hip_runtime.h>
#include <math.h>

#define NB 256
#define NIMG 1561
#define RIRLEN 8000
#define PADI 40
#define NTHREADS 1024
#define NWAVES (NTHREADS / 64)
#define NBKT8 1024        // 8-sample buckets: idx = ((base+40)>>3)+5 in [5,1009]
#define NGRP 63           // groups of 4 streams x 32 samples = 128 samples
#define CHUNK 64          // records per phase-2 work item (per stream window)
#define MAXITEMS 192      // worst case ~149 (63 + 5470/64)

// ---------------------------------------------------------------------------
// Compile-time image-lattice table: all g in [-10,10]^3 with |g|_1 <= 10,
// meshgrid(ij) lexicographic order. Packed:
//   bits 0-4: x+10, 5-9: y+10, 10-14: z+10, 15-19: |g|_1
// ---------------------------------------------------------------------------
struct ImgTab { unsigned int v[NIMG]; };

constexpr ImgTab build_tab() {
    ImgTab t{};
    int n = 0;
    for (int x = -10; x <= 10; ++x)
        for (int y = -10; y <= 10; ++y)
            for (int z = -10; z <= 10; ++z) {
                int ax = x < 0 ? -x : x;
                int ay = y < 0 ? -y : y;
                int az = z < 0 ? -z : z;
                int l1 = ax + ay + az;
                if (l1 <= 10) {
                    t.v[n++] = (unsigned)(x + 10) | ((unsigned)(y + 10) << 5) |
                               ((unsigned)(z + 10) << 10) | ((unsigned)l1 << 15);
                }
            }
    return t;
}

constexpr int tab_count() {
    int n = 0;
    for (int x = -10; x <= 10; ++x)
        for (int y = -10; y <= 10; ++y)
            for (int z = -10; z <= 10; ++z) {
                int ax = x < 0 ? -x : x;
                int ay = y < 0 ? -y : y;
                int az = z < 0 ? -z : z;
                if (ax + ay + az <= 10) ++n;
            }
    return n;
}
static_assert(tab_count() == NIMG, "image count mismatch");

__constant__ ImgTab c_tab = build_tab();

// Record per image (bucket-sorted): (A, B, C, d)
//   A = 0.5*S, B = 0.5*S*cos(pi*d/40), C = 0.5*S*sin(pi*d/40)
//   S = (-1)^dlc * amp * sin(pi*frac)/pi,  d = delay (exact, NON-integer)
// Tap at sample n: (-1)^n * (A + B*cos(pi*n/40) + C*sin(pi*n/40)) / (n-d),
// masked to |n-d| < 40.  frac==0 records are emitted as exact spikes instead.
//
// Phase 2: 32-sample streams, 16 lanes/stream, 2 taps/lane at n0 and n0+16.
// Wave serves 4 streams (one group of 128 samples). Stream s window = records
// with base in [32s-79, 32s+31] -> 8-sample buckets [4s, 4s+14) (idx-shifted).
// Lane-taps = NIMG*112 vs NIMG*144 for the old 64-sample streams (-22%).
// Work item = (group g, chunk c of 64 records); items descending g (LPT-ish);
// partial sums accumulate into a 32 KB LDS accumulator via ds f32 atomics.
//
// LDS aliasing: histogram (1024 ints) and scatter cursors (1024 ints) live in
// the first 8 KB of s_out (dead there until s_out is zeroed after scatter).
__global__ __launch_bounds__(NTHREADS) void
rir_kernel(const float* __restrict__ in, float* __restrict__ out) {
    __shared__ float4 s_rec[NIMG + 1];   // +1 dummy (zero) record  (24992 B)
    __shared__ float  s_out[RIRLEN];     // accumulator (32000 B); aliased early
    __shared__ int    s_start[NBKT8];    // exclusive-scan starts   (4096 B)
    __shared__ int    s_item[MAXITEMS];  // work items              (768 B)
    __shared__ float  s_trpow[11];
    __shared__ int    s_T;
    __shared__ int    s_qnext;
    __shared__ int    s_nspike;
    __shared__ int    s_spike_idx[64];
    __shared__ float  s_spike_amp[64];

    int* const s_hist   = (int*)s_out;          // [0:1024)  dead after scan
    int* const s_cursor = (int*)s_out + 1024;   // [1024:2048) dead after scatter

    const int b   = blockIdx.x;
    const int tid = threadIdx.x;
    const float* p = in + b * 10;

    if (tid < NBKT8) s_hist[tid] = 0;
    if (tid == 0) {
        float tr = sqrtf(1.0f - p[9]);
        float pw = 1.0f;
        for (int k = 0; k <= 10; ++k) { s_trpow[k] = pw; pw *= tr; }
        s_nspike = 0;
        s_qnext  = NWAVES;
        s_rec[NIMG] = make_float4(0.0f, 0.0f, 0.0f, -1.0e6f);  // dummy
    }
    __syncthreads();

    const float rx = p[0], ry = p[1], rz = p[2];
    const float mx = p[3] * rx, my = p[4] * ry, mz = p[5] * rz;
    const float sx = p[6] * rx, sy = p[7] * ry, sz = p[8] * rz;
    const float K = 16000.0f / 343.0f;
    const float INV_PI = 0.31830988618379067154f;

    // ---- phase 1: per-image parameters + bucket histogram ----
    float4 rec[2];
    int ibkt[2]  = {0, 0};
    bool ivalid[2] = {false, false};

    for (int u = 0; u < 2; ++u) {
        int i = tid + u * NTHREADS;
        if (i < NIMG) {
            unsigned v = c_tab.v[i];
            int gx = (int)(v & 31u) - 10;
            int gy = (int)((v >> 5) & 31u) - 10;
            int gz = (int)((v >> 10) & 31u) - 10;
            int l1 = (int)(v >> 15);

            float ix = (gx & 1) ? rx * (float)(gx + 1) - sx : rx * (float)gx + sx;
            float iy = (gy & 1) ? ry * (float)(gy + 1) - sy : ry * (float)gy + sy;
            float iz = (gz & 1) ? rz * (float)(gz + 1) - sz : rz * (float)gz + sz;

            float dx = ix - mx, dy = iy - my, dz = iz - mz;
            float dist = sqrtf(dx * dx + dy * dy + dz * dz);

            float amp  = s_trpow[l1] * __builtin_amdgcn_rcpf(dist);
            float d    = dist * K;
            float dlc  = ceilf(d);
            float frac = dlc - d;                 // exact (Sterbenz)
            int   idlc = (int)dlc;
            int   base = idlc - PADI;

            if (base < RIRLEN) {
                if (frac == 0.0f) {
                    // integer-grid delay: exact single spike of amp at idlc
                    if (idlc < RIRLEN) {
                        int sp = atomicAdd(&s_nspike, 1);
                        if (sp < 64) { s_spike_idx[sp] = idlc; s_spike_amp[sp] = amp; }
                    }
                } else {
                    float spf = (frac < 1.0e-3f) ? frac : (sinpif(frac) * INV_PI);
                    float S   = amp * spf;
                    if (idlc & 1) S = -S;         // (-1)^dlc
                    float hS  = 0.5f * S;
                    float cd  = cospif(d * 0.025f);
                    float sd  = sinpif(d * 0.025f);
                    rec[u] = make_float4(hS, hS * cd, hS * sd, d);
                    ibkt[u]   = ((base + 40) >> 3) + 5;   // in [5,1009]
                    ivalid[u] = true;
                    atomicAdd(&s_hist[ibkt[u]], 1);
                }
            }
        }
    }
    __syncthreads();

    // ---- single-wave exclusive scan of the 1024-bucket histogram ----
    // lane l owns buckets [16l, 16l+16); local prefix + shfl_up wave scan.
    if (tid < 64) {
        int base_i = tid * 16;
        int pre[16];
        int run = 0;
#pragma unroll
        for (int j = 0; j < 16; ++j) {
            int v = s_hist[base_i + j];
            pre[j] = run;
            run += v;
        }
        int t = run;
#pragma unroll
        for (int d2 = 1; d2 < 64; d2 <<= 1) {
            int y = __shfl_up(t, d2);
            if (tid >= d2) t += y;
        }
        int excl = t - run;
#pragma unroll
        for (int j = 0; j < 16; ++j) {
            int idx = base_i + j;
            int sv  = excl + pre[j];              // exclusive prefix at idx
            s_start[idx]  = sv;
            s_cursor[idx] = sv;
        }
    }
    __syncthreads();

    // ---- scatter records into bucket-sorted order ----
    for (int u = 0; u < 2; ++u) {
        if (ivalid[u]) {
            int pos = atomicAdd(&s_cursor[ibkt[u]], 1);
            s_rec[pos] = rec[u];
        }
    }
    __syncthreads();

    // ---- wave 0: build item list; all threads: zero s_out (kills hist/cursor)
    // lane l handles group g = 62-l  ->  items emitted in DESCENDING g order.
    if (tid < 64) {
        int nch = 0, g = 62 - tid;
        if (tid < NGRP) {
            int bs = 16 * g;
            int l0 = s_start[bs + 14] - s_start[bs];
            int l1 = s_start[bs + 18] - s_start[bs + 4];
            int l2 = s_start[bs + 22] - s_start[bs + 8];
            int l3 = s_start[bs + 26] - s_start[bs + 12];
            int ml = (l0 > l1) ? l0 : l1;
            ml = (l2 > ml) ? l2 : ml;
            ml = (l3 > ml) ? l3 : ml;
            nch = (ml + CHUNK - 1) >> 6;
        }
        int run = nch;
#pragma unroll
        for (int d2 = 1; d2 < 64; d2 <<= 1) {
            int y = __shfl_up(run, d2);
            if (tid >= d2) run += y;
        }
        int excl = run - nch;
        int tot  = __shfl(run, 63);
        if (tid == 0) s_T = (tot < MAXITEMS) ? tot : MAXITEMS;
        for (int c = 0; c < nch; ++c)
            if (excl + c < MAXITEMS) s_item[excl + c] = (g << 5) | c;
    }
    for (int i = tid; i < RIRLEN; i += NTHREADS) s_out[i] = 0.0f;
    __syncthreads();

    // ---- phase 2: gather. item = (group, chunk); wave serves 4 streams ----
    // lanes [16j,16j+16) -> stream 4g+j; lane owns samples n0 and n0+16.
    const int wave = tid >> 6;
    const int lane = tid & 63;
    const int j    = lane >> 4;
    const int l4   = lane & 15;
    const float sgn = (l4 & 1) ? -1.0f : 1.0f;    // (-1)^n0, n0 parity == l4 parity
    const float c16 = 0.30901699437494742410f;    // cos(0.4*pi)
    const float s16 = 0.95105651629515357212f;    // sin(0.4*pi)
    float* __restrict__ ob = out + (size_t)b * RIRLEN;
    const int T = s_T;

    int idx = wave;
    while (idx < T) {
        const int item = s_item[idx];
        const int g = item >> 5, c = item & 31;
        const int n0 = (g << 7) + (j << 5) + l4;
        const int n1 = n0 + 16;
        const float fn0 = (float)n0;
        const float cn0 = cospif(fn0 * 0.025f), sn0 = sinpif(fn0 * 0.025f);
        const float cnn1 = cn0 * c16 - sn0 * s16; // cos(pi*n1/40)
        const float snn1 = sn0 * c16 + cn0 * s16; // sin(pi*n1/40)

        const int bs = 16 * g;
        const int l0 = s_start[bs + 14] - s_start[bs];
        const int l1 = s_start[bs + 18] - s_start[bs + 4];
        const int l2 = s_start[bs + 22] - s_start[bs + 8];
        const int l3 = s_start[bs + 26] - s_start[bs + 12];
        int lmn = (l0 < l1) ? l0 : l1; lmn = (l2 < lmn) ? l2 : lmn; lmn = (l3 < lmn) ? l3 : lmn;
        int lmx = (l0 > l1) ? l0 : l1; lmx = (l2 > lmx) ? l2 : lmx; lmx = (l3 > lmx) ? l3 : lmx;
        const int st  = c << 6;                   // c * CHUNK
        int e0 = lmn - st; e0 = (e0 < 0) ? 0 : ((e0 > CHUNK) ? CHUNK : e0);
        int e1 = lmx - st; e1 = (e1 > CHUNK) ? CHUNK : e1;   // >0 since c<nch
        const int lo = s_start[bs + 4 * j] + st;  // per-lane stream window
        const int hi = s_start[bs + 4 * j + 14];

        float acc0 = 0.0f, acc1 = 0.0f;
        // main loop: all four streams in-range within this chunk, no select.
        // shared-rcp trick: 1/x0 = x1*rcp(x0*x1), 1/x1 = x0*rcp(x0*x1)
        // (product never 0 since d is non-integer).
#pragma clang loop unroll_count(4)
        for (int it = 0; it < e0; ++it) {
            float4 r = s_rec[lo + it];
            float x0 = fn0 - r.w;                 // never 0 (d non-integer)
            float x1 = x0 + 16.0f;
            float pr = __builtin_amdgcn_rcpf(x0 * x1);
            float t0 = fmaf(r.y, cn0, r.x);  t0 = fmaf(r.z, sn0, t0);
            float t1 = fmaf(r.y, cnn1, r.x); t1 = fmaf(r.z, snn1, t1);
            t0 = (fabsf(x0) < 40.0f) ? t0 : 0.0f; // hann support mask
            t1 = (fabsf(x1) < 40.0f) ? t1 : 0.0f;
            acc0 = fmaf(t0 * x1, pr, acc0);
            acc1 = fmaf(t1 * x0, pr, acc1);
        }
        // fixup: longer streams continue, exhausted streams read dummy record
#pragma clang loop unroll_count(2)
        for (int it = e0; it < e1; ++it) {
            int k = lo + it;
            float4 r = s_rec[(k < hi) ? k : NIMG];
            float x0 = fn0 - r.w;
            float x1 = x0 + 16.0f;
            float pr = __builtin_amdgcn_rcpf(x0 * x1);
            float t0 = fmaf(r.y, cn0, r.x);  t0 = fmaf(r.z, sn0, t0);
            float t1 = fmaf(r.y, cnn1, r.x); t1 = fmaf(r.z, snn1, t1);
            t0 = (fabsf(x0) < 40.0f) ? t0 : 0.0f;
            t1 = (fabsf(x1) < 40.0f) ? t1 : 0.0f;
            acc0 = fmaf(t0 * x1, pr, acc0);
            acc1 = fmaf(t1 * x0, pr, acc1);
        }
        if (n0 < RIRLEN) atomicAdd(&s_out[n0], acc0 * sgn);
        if (n1 < RIRLEN) atomicAdd(&s_out[n1], acc1 * sgn);

        // steal next item
        int nq;
        if (lane == 0) nq = atomicAdd(&s_qnext, 1);
        idx = __shfl(nq, 0);
    }

    // ---- spikes (frac==0, rare): add into LDS accumulator ----
    __syncthreads();
    int nsp = s_nspike; nsp = (nsp < 64) ? nsp : 64;
    if (tid < nsp) atomicAdd(&s_out[s_spike_idx[tid]], s_spike_amp[tid]);
    __syncthreads();

    // ---- final copy LDS -> global, vectorized ----
    float4* __restrict__ o4 = (float4*)ob;
    const float4* s4 = (const float4*)s_out;
#pragma unroll 2
    for (int i = tid; i < RIRLEN / 4; i += NTHREADS) o4[i] = s4[i];

    // time-of-arrival
    if (tid == 0) {
        float dx = mx - sx, dy = my - sy, dz = mz - sz;
        out[(size_t)NB * RIRLEN + b] = 40.0f + sqrtf(dx * dx + dy * dy + dz * dz) * K;
    }
}

extern "C" void kernel_launch(void* const* d_in, const int* in_sizes, int n_in,
                              void* d_out, int out_size, void* d_ws, size_t ws_size,
                              hipStream_t stream) {
    const float* in = (const float*)d_in[0];
    float* out = (float*)d_out;
    rir_kernel<<<dim3(NB), dim3(NTHREADS), 0, stream>>>(in, out);
}